// Round 1
// baseline (391.291 us; speedup 1.0000x reference)
//
#include <hip/hip_runtime.h>
#include <hip/hip_bf16.h>

typedef __bf16 bf16;
typedef __bf16 bf16x4 __attribute__((ext_vector_type(4)));
typedef __bf16 bf16x8 __attribute__((ext_vector_type(8)));
typedef float floatx4 __attribute__((ext_vector_type(4)));

#define EMBED 1024
#define VOCAB 32000
#define BB    4
#define SS    4096
#define NTOK  (BB * SS)   // 16384
#define NKV   2048        // K and V concatenated
#define NSEG  16          // d-segments for partial-buffer GEMMs

// ---- async global->LDS, 16B per lane (lane-contiguous LDS dest required) ----
__device__ __forceinline__ void async_copy16(void* lds, const void* g) {
    __builtin_amdgcn_global_load_lds(
        (const __attribute__((address_space(1))) unsigned int*)g,
        (__attribute__((address_space(3))) unsigned int*)lds, 16, 0, 0);
}

// ============================================================================
// K1: gather h = embed[x] -> bf16; stash last token per batch (fp32) as both
// q-input (h_last) and residual init (h_final).
// ============================================================================
__global__ void gather_embed(const int* __restrict__ x,
                             const float* __restrict__ embed,
                             bf16* __restrict__ h,
                             float* __restrict__ h_last,
                             float* __restrict__ h_final) {
    int t = blockIdx.x;            // 16384 tokens
    int tid = threadIdx.x;         // 256
    int row = x[t];                // broadcast scalar load
    const float4* src = (const float4*)(embed + (size_t)row * EMBED);
    float4 v = src[tid];
    bf16x4 o; o.x = (bf16)v.x; o.y = (bf16)v.y; o.z = (bf16)v.z; o.w = (bf16)v.w;
    *(bf16x4*)(h + (size_t)t * EMBED + tid * 4) = o;
    if ((t & (SS - 1)) == SS - 1) {
        int b = t >> 12;
        *(float4*)(h_last  + b * EMBED + tid * 4) = v;
        *(float4*)(h_final + b * EMBED + tid * 4) = v;
    }
}

// ============================================================================
// K2: transpose+convert qkv_w[:, 1024:3072] -> WkvT[n][d] bf16 (2048 x 1024)
// ============================================================================
__global__ void wkvt_transpose(const float* __restrict__ qkv_w,
                               bf16* __restrict__ WkvT) {
    __shared__ float T[32][33];
    int n0 = blockIdx.x * 32, d0 = blockIdx.y * 32;
    int tid = threadIdx.x;
    int c = tid & 31, r = tid >> 5;
#pragma unroll
    for (int i = 0; i < 4; ++i) {
        int d = r + i * 8;
        T[c][d] = qkv_w[(size_t)(d0 + d) * (3 * EMBED) + EMBED + n0 + c];
    }
    __syncthreads();
#pragma unroll
    for (int i = 0; i < 4; ++i) {
        int n = r + i * 8;
        WkvT[(size_t)(n0 + n) * EMBED + d0 + c] = (bf16)T[n][c];
    }
}

// ============================================================================
// K3: q partials. qpart[seg][b][j] = sum_{d in seg} h_last[b][d]*qkv_w[d][j]
// ============================================================================
__global__ void q_gemm(const float* __restrict__ h_last,
                       const float* __restrict__ qkv_w,
                       float* __restrict__ qpart) {
    __shared__ float hs[BB * 64];
    int tid = threadIdx.x;
    int seg = blockIdx.x, d0 = seg * 64;
    hs[tid] = h_last[(tid >> 6) * EMBED + d0 + (tid & 63)];
    __syncthreads();
    int j0 = tid * 4;                           // 0..1023
    floatx4 acc[BB];
#pragma unroll
    for (int b = 0; b < BB; ++b) acc[b] = (floatx4)0.0f;
#pragma unroll 4
    for (int dd = 0; dd < 64; ++dd) {
        float4 w = *(const float4*)(qkv_w + (size_t)(d0 + dd) * (3 * EMBED) + j0);
#pragma unroll
        for (int b = 0; b < BB; ++b) {
            float hv = hs[b * 64 + dd];
            acc[b][0] += hv * w.x; acc[b][1] += hv * w.y;
            acc[b][2] += hv * w.z; acc[b][3] += hv * w.w;
        }
    }
#pragma unroll
    for (int b = 0; b < BB; ++b)
        *(floatx4*)(qpart + ((size_t)seg * BB + b) * EMBED + j0) = acc[b];
}

// K3b: q[b][d] = qkv_b[d] + sum_seg qpart[seg][b][d]
__global__ void q_reduce(const float* __restrict__ qpart,
                         const float* __restrict__ qkv_b,
                         float* __restrict__ q) {
    int k = blockIdx.x * 256 + threadIdx.x;     // 4096
    int b = k >> 10, d = k & (EMBED - 1);
    float s = qkv_b[d];
#pragma unroll
    for (int sg = 0; sg < NSEG; ++sg) s += qpart[((size_t)sg * BB + b) * EMBED + d];
    q[k] = s;
}

// ============================================================================
// K4: the big GEMM — 256x256 tile, BK=64 (two k-halves of 32), 8 waves
// (2M x 4N), 8-phase schedule with counted vmcnt (T3+T4) + setprio (T5).
// LDS K-split halves [256 rows][32 k] -> 64B row stride: wave ds_read_b128
// footprint covers each 1KiB uniformly over all 32 banks, so NO swizzle is
// needed and global_load_lds keeps a linear lane-contiguous dest.
//
// Per 4-phase group G_k (reads tile k from parity slot k&1):
//   P1: rd A(kh0,m-half0)+B(kh0)  | stage A-kh1(k+1) | bar;lgkm0;16 MFMA;bar
//   P2: rd A(kh0,m-half1)         | stage B-kh1(k+1) | ...;vmcnt(8);bar
//   P3: rd A(kh1,m-half0)+B(kh1)  | stage A-kh0(k+2) | ...
//   P4: rd A(kh1,m-half1)         | stage B-kh0(k+2) | ...;vmcnt(8);bar
// Steady state: 4 halves (8 loads/thread) in flight; vmcnt never drained to 0
// in the main loop. Tail peeled with exact vmcnt(8)/(4)/(0).
// ============================================================================
__global__ __launch_bounds__(512, 2) void gemm_kv(
    const bf16* __restrict__ A,    // 16384 x 1024 row-major
    const bf16* __restrict__ BT,   // 2048 x 1024
    const float* __restrict__ bias,// 2048
    bf16* __restrict__ C) {        // 16384 x 2048
    __shared__ __align__(16) bf16 SA[2][2][256 * 32];  // [khalf][parity][row*32+k]
    __shared__ __align__(16) bf16 SB[2][2][256 * 32];  // 128 KiB total

    const int tid  = threadIdx.x;          // 512
    const int wave = tid >> 6, lane = tid & 63;
    const int wm = wave >> 2, wn = wave & 3;        // 2 x 4 wave grid
    const int l16 = lane & 15, quad = lane >> 4;
    const int a_base = (wm * 128 + l16) * 32 + quad * 8;
    const int b_base = (wn * 64  + l16) * 32 + quad * 8;

    const bf16* Abase = A  + (size_t)blockIdx.x * 256 * EMBED;
    const bf16* Bbase = BT + (size_t)blockIdx.y * 256 * EMBED;

    floatx4 acc[8][4];
#pragma unroll
    for (int m = 0; m < 8; ++m)
#pragma unroll
        for (int n = 0; n < 4; ++n) acc[m][n] = (floatx4)0.0f;

    bf16x8 af[4], bfr[4];

#define STAGE_A(HALF, KT) do { \
    int c_ = wave * 128 + lane; \
    async_copy16(&SA[HALF][(KT) & 1][c_ * 8], \
        Abase + (size_t)(c_ >> 2) * EMBED + (KT) * 64 + (HALF) * 32 + (c_ & 3) * 8); \
    c_ += 64; \
    async_copy16(&SA[HALF][(KT) & 1][c_ * 8], \
        Abase + (size_t)(c_ >> 2) * EMBED + (KT) * 64 + (HALF) * 32 + (c_ & 3) * 8); \
} while (0)

#define STAGE_B(HALF, KT) do { \
    int c_ = wave * 128 + lane; \
    async_copy16(&SB[HALF][(KT) & 1][c_ * 8], \
        Bbase + (size_t)(c_ >> 2) * EMBED + (KT) * 64 + (HALF) * 32 + (c_ & 3) * 8); \
    c_ += 64; \
    async_copy16(&SB[HALF][(KT) & 1][c_ * 8], \
        Bbase + (size_t)(c_ >> 2) * EMBED + (KT) * 64 + (HALF) * 32 + (c_ & 3) * 8); \
} while (0)

#define RD_A(KS, PAR, MH) do { \
    const bf16* pa_ = &SA[KS][PAR][a_base + (MH) * 2048]; \
    _Pragma("unroll") \
    for (int mf_ = 0; mf_ < 4; ++mf_) af[mf_] = *(const bf16x8*)(pa_ + mf_ * 512); \
} while (0)

#define RD_B(KS, PAR) do { \
    const bf16* pb_ = &SB[KS][PAR][b_base]; \
    _Pragma("unroll") \
    for (int nf_ = 0; nf_ < 4; ++nf_) bfr[nf_] = *(const bf16x8*)(pb_ + nf_ * 512); \
} while (0)

#define MFMA16(MH) do { \
    __builtin_amdgcn_s_setprio(1); \
    _Pragma("unroll") \
    for (int mf_ = 0; mf_ < 4; ++mf_) \
    _Pragma("unroll") \
    for (int nf_ = 0; nf_ < 4; ++nf_) \
        acc[(MH) * 4 + mf_][nf_] = __builtin_amdgcn_mfma_f32_16x16x32_bf16( \
            af[mf_], bfr[nf_], acc[(MH) * 4 + mf_][nf_], 0, 0, 0); \
    __builtin_amdgcn_s_setprio(0); \
} while (0)

#define BARLG() do { __builtin_amdgcn_s_barrier(); \
    asm volatile("s_waitcnt lgkmcnt(0)" ::: "memory"); } while (0)
#define BAR()   __builtin_amdgcn_s_barrier()
#define WAIT8() do { __builtin_amdgcn_sched_barrier(0); \
    asm volatile("s_waitcnt vmcnt(8)" ::: "memory"); } while (0)
#define WAIT4() do { __builtin_amdgcn_sched_barrier(0); \
    asm volatile("s_waitcnt vmcnt(4)" ::: "memory"); } while (0)
#define WAIT0() do { __builtin_amdgcn_sched_barrier(0); \
    asm volatile("s_waitcnt vmcnt(0)" ::: "memory"); } while (0)
#define NOSTG() do { } while (0)

#define GROUP(PAR, S1, S2, S3, S4, W2, W4) do { \
    RD_A(0, PAR, 0); RD_B(0, PAR); S1; BARLG(); MFMA16(0); BAR(); \
    RD_A(0, PAR, 1);               S2; BARLG(); MFMA16(1); W2; BAR(); \
    RD_A(1, PAR, 0); RD_B(1, PAR); S3; BARLG(); MFMA16(0); BAR(); \
    RD_A(1, PAR, 1);               S4; BARLG(); MFMA16(1); W4; BAR(); \
} while (0)

    // prologue: 6 halves (12 loads) in flight; wait oldest 4 (A0/B0 of tile 0)
    STAGE_A(0, 0); STAGE_B(0, 0);
    STAGE_A(1, 0); STAGE_B(1, 0);
    STAGE_A(0, 1); STAGE_B(0, 1);
    __builtin_amdgcn_sched_barrier(0);
    asm volatile("s_waitcnt vmcnt(8)" ::: "memory");
    BAR();

#pragma unroll 1
    for (int kk = 0; kk < 7; ++kk) {            // tiles 0..13, fully regular
        const int k0 = kk * 2, k1 = k0 + 1;
        GROUP(0, STAGE_A(1, k0 + 1), STAGE_B(1, k0 + 1),
                 STAGE_A(0, k0 + 2), STAGE_B(0, k0 + 2), WAIT8(), WAIT8());
        GROUP(1, STAGE_A(1, k1 + 1), STAGE_B(1, k1 + 1),
                 STAGE_A(0, k1 + 2), STAGE_B(0, k1 + 2), WAIT8(), WAIT8());
    }
    // tile 14: stage only the last two halves of tile 15
    GROUP(0, STAGE_A(1, 15), STAGE_B(1, 15), NOSTG(), NOSTG(), WAIT8(), WAIT4());
    // tile 15: nothing left to stage
    GROUP(1, NOSTG(), NOSTG(), NOSTG(), NOSTG(), WAIT0(), NOSTG());

    // epilogue: fragment fm covers rows fm*16.. within the wave's 128-row band
    const int crow0 = blockIdx.x * 256 + wm * 128;
    const int ccol0 = blockIdx.y * 256 + wn * 64;
    float bsv[4];
#pragma unroll
    for (int nf = 0; nf < 4; ++nf) bsv[nf] = bias[ccol0 + nf * 16 + l16];
#pragma unroll
    for (int fm = 0; fm < 8; ++fm)
#pragma unroll
        for (int nf = 0; nf < 4; ++nf) {
            int col = ccol0 + nf * 16 + l16;
#pragma unroll
            for (int r = 0; r < 4; ++r) {
                int row = crow0 + fm * 16 + quad * 4 + r;
                C[(size_t)row * NKV + col] = (bf16)(acc[fm][nf][r] + bsv[nf]);
            }
        }
#undef STAGE_A
#undef STAGE_B
#undef RD_A
#undef RD_B
#undef MFMA16
#undef BARLG
#undef BAR
#undef WAIT8
#undef WAIT4
#undef WAIT0
#undef NOSTG
#undef GROUP
}

// ============================================================================
// K5: logits[b][t] = (q[b] . K[b,t]) / 32 — one wave per t; q staged in LDS.
// ============================================================================
__global__ void attn_logits(const bf16* __restrict__ KV,
                            const float* __restrict__ q,
                            float* __restrict__ logits) {
    __shared__ float qs[EMBED];
    int b = blockIdx.x >> 10;                   // 1024 blocks per batch
    int t = (blockIdx.x & 1023) * 4 + (threadIdx.x >> 6);
    int lane = threadIdx.x & 63;
    *(float4*)(qs + threadIdx.x * 4) = *(const float4*)(q + b * EMBED + threadIdx.x * 4);
    __syncthreads();
    const bf16* Krow = KV + (size_t)(b * SS + t) * NKV;
    float sum = 0.0f;
#pragma unroll
    for (int i = 0; i < 2; ++i) {
        int d0 = i * 512 + lane * 8;
        bf16x8 kv8 = *(const bf16x8*)(Krow + d0);
        float4 qa = *(const float4*)(qs + d0);
        float4 qc = *(const float4*)(qs + d0 + 4);
        sum += qa.x * (float)kv8[0] + qa.y * (float)kv8[1] +
               qa.z * (float)kv8[2] + qa.w * (float)kv8[3] +
               qc.x * (float)kv8[4] + qc.y * (float)kv8[5] +
               qc.z * (float)kv8[6] + qc.w * (float)kv8[7];
    }
#pragma unroll
    for (int o = 32; o; o >>= 1) sum += __shfl_down(sum, o);
    if (lane == 0) logits[b * SS + t] = sum * 0.03125f;
}

// ============================================================================
// K6: softmax over 4096 per batch — one 1024-thread block per batch.
// ============================================================================
__global__ void softmax_k(const float* __restrict__ logits,
                          float* __restrict__ wts) {
    int b = blockIdx.x, tid = threadIdx.x;      // 1024 threads
    __shared__ float redm[16], reds[16];
    const float* l = logits + b * SS;
    float x0 = l[tid], x1 = l[tid + 1024], x2 = l[tid + 2048], x3 = l[tid + 3072];
    float m = fmaxf(fmaxf(x0, x1), fmaxf(x2, x3));
#pragma unroll
    for (int o = 32; o; o >>= 1) m = fmaxf(m, __shfl_down(m, o));
    if ((tid & 63) == 0) redm[tid >> 6] = m;
    __syncthreads();
    float M = redm[0];
#pragma unroll
    for (int i = 1; i < 16; ++i) M = fmaxf(M, redm[i]);
    float e0 = expf(x0 - M), e1 = expf(x1 - M), e2 = expf(x2 - M), e3 = expf(x3 - M);
    float s = e0 + e1 + e2 + e3;
#pragma unroll
    for (int o = 32; o; o >>= 1) s += __shfl_down(s, o);
    if ((tid & 63) == 0) reds[tid >> 6] = s;
    __syncthreads();
    float S = 0.0f;
#pragma unroll
    for (int i = 0; i < 16; ++i) S += reds[i];
    float inv = 1.0f / S;
    float* w = wts + b * SS;
    w[tid] = e0 * inv; w[tid + 1024] = e1 * inv;
    w[tid + 2048] = e2 * inv; w[tid + 3072] = e3 * inv;
}

// ============================================================================
// K7: h_final[b] += sum_t wts[b][t] * V[b,t]
// ============================================================================
__global__ void attn_av(const bf16* __restrict__ KV,
                        const float* __restrict__ wts,
                        float* __restrict__ h_final) {
    int b = blockIdx.x >> 6, ts = blockIdx.x & 63;
    int tid = threadIdx.x;
    __shared__ float wsh[64];
    if (tid < 64) wsh[tid] = wts[b * SS + ts * 64 + tid];
    __syncthreads();
    int d = tid * 4;
    const bf16* Vb = KV + (size_t)(b * SS + ts * 64) * NKV + EMBED + d;
    float a0 = 0, a1 = 0, a2 = 0, a3 = 0;
#pragma unroll 4
    for (int j = 0; j < 64; ++j) {
        bf16x4 v = *(const bf16x4*)(Vb + (size_t)j * NKV);
        float w = wsh[j];
        a0 += w * (float)v.x; a1 += w * (float)v.y;
        a2 += w * (float)v.z; a3 += w * (float)v.w;
    }
    atomicAdd(h_final + b * EMBED + d + 0, a0);
    atomicAdd(h_final + b * EMBED + d + 1, a1);
    atomicAdd(h_final + b * EMBED + d + 2, a2);
    atomicAdd(h_final + b * EMBED + d + 3, a3);
}

// ============================================================================
// K8: out partials. opart[seg][b][j] = sum_{d in seg} h_final[b][d]*out_w[d][j]
// ============================================================================
__global__ void out_gemm(const float* __restrict__ h_final,
                         const float* __restrict__ out_w,
                         float* __restrict__ opart) {
    __shared__ float hs[BB * 64];
    int tid = threadIdx.x;
    int seg = blockIdx.y, d0 = seg * 64;
    hs[tid] = h_final[(tid >> 6) * EMBED + d0 + (tid & 63)];
    __syncthreads();
    int j0 = blockIdx.x * 1024 + tid * 4;
    if (j0 >= VOCAB) return;                    // tail block: tid >= 64 idle
    floatx4 acc[BB];
#pragma unroll
    for (int b = 0; b < BB; ++b) acc[b] = (floatx4)0.0f;
#pragma unroll 4
    for (int dd = 0; dd < 64; ++dd) {
        float4 w = *(const float4*)(out_w + (size_t)(d0 + dd) * VOCAB + j0);
#pragma unroll
        for (int b = 0; b < BB; ++b) {
            float hv = hs[b * 64 + dd];
            acc[b][0] += hv * w.x; acc[b][1] += hv * w.y;
            acc[b][2] += hv * w.z; acc[b][3] += hv * w.w;
        }
    }
#pragma unroll
    for (int b = 0; b < BB; ++b)
        *(floatx4*)(opart + ((size_t)seg * BB + b) * VOCAB + j0) = acc[b];
}

// K8b: out[b][j] = out_b[j] + sum_seg opart[seg][b][j]
__global__ void out_reduce(const float* __restrict__ opart,
                           const float* __restrict__ out_b,
                           float* __restrict__ out) {
    int i = blockIdx.x * 256 + threadIdx.x;     // 128000
    if (i >= BB * VOCAB) return;
    int b = i / VOCAB, j = i - b * VOCAB;
    float s = out_b[j];
#pragma unroll
    for (int sg = 0; sg < NSEG; ++sg) s += opart[((size_t)sg * BB + b) * VOCAB + j];
    out[i] = s;
}

// ============================================================================
extern "C" void kernel_launch(void* const* d_in, const int* in_sizes, int n_in,
                              void* d_out, int out_size, void* d_ws, size_t ws_size,
                              hipStream_t stream) {
    const int*   x      = (const int*)d_in[0];
    const float* embed  = (const float*)d_in[1];
    const float* qkv_w  = (const float*)d_in[2];
    const float* qkv_b  = (const float*)d_in[3];
    const float* out_w  = (const float*)d_in[4];
    const float* out_b  = (const float*)d_in[5];
    float* out = (float*)d_out;

    char* ws = (char*)d_ws;
    bf16*  h       = (bf16*)(ws);                         // 32 MiB
    float* opart   = (float*)(ws);                        // 8 MiB, overlays h (h dead after gemm_kv)
    bf16*  KV      = (bf16*)(ws + 33554432);              // 64 MiB
    bf16*  WkvT    = (bf16*)(ws + 100663296);             // 4 MiB
    float* h_last  = (float*)(ws + 104857600);            // 16 KiB
    float* h_final = (float*)(ws + 104873984);            // 16 KiB
    float* q       = (float*)(ws + 104890368);            // 16 KiB
    float* logits  = (float*)(ws + 104906752);            // 64 KiB
    float* wts     = (float*)(ws + 104972288);            // 64 KiB
    float* qpart   = (float*)(ws + 105037824);            // 256 KiB

    gather_embed<<<NTOK, 256, 0, stream>>>(x, embed, h, h_last, h_final);
    wkvt_transpose<<<dim3(64, 32), 256, 0, stream>>>(qkv_w, WkvT);
    q_gemm<<<NSEG, 256, 0, stream>>>(h_last, qkv_w, qpart);
    q_reduce<<<16, 256, 0, stream>>>(qpart, qkv_b, q);
    gemm_kv<<<dim3(NTOK / 256, NKV / 256), 512, 0, stream>>>(
        h, WkvT, qkv_b + EMBED, KV);
    attn_logits<<<SS, 256, 0, stream>>>(KV, q, logits);
    softmax_k<<<BB, 1024, 0, stream>>>(logits, wts);
    attn_av<<<256, 256, 0, stream>>>(KV, wts, h_final);
    out_gemm<<<dim3(32, NSEG), 256, 0, stream>>>(h_final, out_w, opart);
    out_reduce<<<(BB * VOCAB + 255) / 256, 256, 0, stream>>>(opart, out_b, out);
}